// Round 1
// baseline (293.479 us; speedup 1.0000x reference)
//
#include <hip/hip_runtime.h>
#include <stdint.h>

typedef unsigned short u16;
typedef unsigned int u32;

constexpr int CB = 2, CT = 2048, CH = 16, CDH = 64, CD = 1024;

typedef __attribute__((ext_vector_type(8))) short bf16x8;
typedef __attribute__((ext_vector_type(4))) float f32x4;

typedef __attribute__((address_space(1))) const u32 as1_cu32;
typedef __attribute__((address_space(3))) u32 as3_u32;

__device__ __forceinline__ void gload_lds16(const void* g, void* l) {
  __builtin_amdgcn_global_load_lds((as1_cu32*)g, (as3_u32*)l, 16, 0, 0);
}

// fp32 -> bf16 round-to-nearest-even (finite inputs only)
__device__ __forceinline__ u16 f2b(float f) {
  u32 x = __float_as_uint(f);
  u32 r = (x + 0x7fffu + ((x >> 16) & 1u)) >> 16;
  return (u16)r;
}

__device__ __forceinline__ void store_out(u16* p, float v) { *p = f2b(v); }
__device__ __forceinline__ void store_out(float* p, float v) { *p = v; }

// ---------------- cast x (fp32 -> bf16) ----------------
__global__ __launch_bounds__(256) void cast_bf16_k(const float* __restrict__ x,
                                                   u16* __restrict__ o, int n4) {
  int i = blockIdx.x * 256 + threadIdx.x;
  if (i < n4) {
    float4 v = ((const float4*)x)[i];
    ushort4 r;
    r.x = f2b(v.x); r.y = f2b(v.y); r.z = f2b(v.z); r.w = f2b(v.w);
    ((ushort4*)o)[i] = r;
  }
}

// ------------- transpose + cast W [K][N] fp32 -> Wt [N][K] bf16 -------------
__global__ __launch_bounds__(256) void transpose_cast_k(const float* __restrict__ W,
                                                        u16* __restrict__ Wt) {
  __shared__ float tile[32][33];
  int bx = blockIdx.x * 32, by = blockIdx.y * 32;
  int tx = threadIdx.x & 31, ty = threadIdx.x >> 5;  // 32 x 8
  #pragma unroll
  for (int i = ty; i < 32; i += 8) tile[i][tx] = W[(size_t)(by + i) * CD + bx + tx];
  __syncthreads();
  #pragma unroll
  for (int i = ty; i < 32; i += 8)
    Wt[(size_t)(bx + i) * CD + by + tx] = f2b(tile[tx][i]);
}

// ---------------- GEMM: C[M,1024-sub] = A[M,K]bf16 @ Bt[N,K]bf16^T ----------------
// 128x128 tile, BK=32, 256 threads (2x2 waves, each 64x64 via 4x4 MFMA tiles).
// XOR swizzle on 16B chunks: LDS[row][c] holds global chunk (row, c ^ (row&3)).
template <typename OT>
__global__ __launch_bounds__(256) void gemm_bt_k(const u16* __restrict__ A,
                                                 const u16* __restrict__ Bt,
                                                 OT* __restrict__ Cout,
                                                 int K, size_t subStride) {
  __shared__ __align__(16) u16 As[128 * 32];
  __shared__ __align__(16) u16 Bs[128 * 32];
  int t = threadIdx.x;
  int lane = t & 63, w = t >> 6;
  int m = lane & 15, quad = lane >> 4;
  int wrow = w >> 1, wcol = w & 1;
  int m0 = blockIdx.y * 128, n0 = blockIdx.x * 128;

  f32x4 acc[4][4];
  #pragma unroll
  for (int i = 0; i < 4; i++)
    #pragma unroll
    for (int j = 0; j < 4; j++) acc[i][j] = (f32x4){0.f, 0.f, 0.f, 0.f};

  for (int k0 = 0; k0 < K; k0 += 32) {
    __syncthreads();
    #pragma unroll
    for (int p = 0; p < 2; p++) {
      int idx = p * 256 + t;
      int row = idx >> 2, c = idx & 3;
      int cc = c ^ (row & 3);
      gload_lds16(A + (size_t)(m0 + row) * K + k0 + cc * 8,
                  As + (size_t)(p * 256 + (t & 192)) * 8);
      gload_lds16(Bt + (size_t)(n0 + row) * K + k0 + cc * 8,
                  Bs + (size_t)(p * 256 + (t & 192)) * 8);
    }
    __syncthreads();
    bf16x8 af[4], bfr[4];
    #pragma unroll
    for (int mt = 0; mt < 4; mt++) {
      int r = wrow * 64 + mt * 16 + m;
      af[mt] = *(const bf16x8*)&As[r * 32 + ((quad ^ (r & 3)) * 8)];
    }
    #pragma unroll
    for (int nt = 0; nt < 4; nt++) {
      int r = wcol * 64 + nt * 16 + m;
      bfr[nt] = *(const bf16x8*)&Bs[r * 32 + ((quad ^ (r & 3)) * 8)];
    }
    #pragma unroll
    for (int mt = 0; mt < 4; mt++)
      #pragma unroll
      for (int nt = 0; nt < 4; nt++)
        acc[mt][nt] = __builtin_amdgcn_mfma_f32_16x16x32_bf16(af[mt], bfr[nt],
                                                              acc[mt][nt], 0, 0, 0);
  }

  #pragma unroll
  for (int mt = 0; mt < 4; mt++) {
    #pragma unroll
    for (int nt = 0; nt < 4; nt++) {
      int c = n0 + wcol * 64 + nt * 16 + m;
      OT* outp = Cout + (size_t)(c >> 10) * subStride + (c & 1023);
      #pragma unroll
      for (int rr = 0; rr < 4; rr++) {
        int r = m0 + wrow * 64 + mt * 16 + quad * 4 + rr;
        store_out(outp + (size_t)r * CD, acc[mt][nt][rr]);
      }
    }
  }
}

// ---------------- flash attention ----------------
// grid (T/64, H, B), 256 threads = 4 waves; wave w owns q-rows [w*16, w*16+16).
__global__ __launch_bounds__(256) void attn_k(const u16* __restrict__ Qb,
                                              const u16* __restrict__ Kb,
                                              const u16* __restrict__ Vb,
                                              const int* __restrict__ mask,
                                              u16* __restrict__ Ob) {
  __shared__ __align__(16) u16 Qs[64 * 64];
  __shared__ __align__(16) u16 Ks[64 * 64];
  __shared__ __align__(16) u16 Vs[64 * 72];  // V^T [dh][key], padded stride 72
  __shared__ __align__(16) u16 Ps[64 * 72];  // P [q][key], padded stride 72
  int t = threadIdx.x, lane = t & 63, w = t >> 6;
  int m = lane & 15, quad = lane >> 4;
  int qt = blockIdx.x, h = blockIdx.y, b = blockIdx.z;

  const u16* Qg = Qb + ((size_t)(b * CT + qt * 64)) * CD + h * CDH;
  #pragma unroll
  for (int p = 0; p < 2; p++) {
    int idx = p * 256 + t;
    int row = idx >> 3, c = idx & 7;
    int cc = c ^ (row & 7);
    gload_lds16(Qg + (size_t)row * CD + cc * 8, Qs + (size_t)(p * 256 + (t & 192)) * 8);
  }
  __syncthreads();
  bf16x8 qf[2];
  {
    int qrow = w * 16 + m;
    #pragma unroll
    for (int kf = 0; kf < 2; kf++) {
      int ch = quad + kf * 4;
      qf[kf] = *(const bf16x8*)&Qs[qrow * 64 + ((ch ^ (qrow & 7)) * 8)];
    }
  }

  float m_i[4], l_i[4];
  f32x4 oacc[4];
  #pragma unroll
  for (int r = 0; r < 4; r++) { m_i[r] = -3e38f; l_i[r] = 0.f; }
  #pragma unroll
  for (int j = 0; j < 4; j++) oacc[j] = (f32x4){0.f, 0.f, 0.f, 0.f};

  const int* mk = mask + b * CT;

  for (int kv = 0; kv < CT; kv += 64) {
    __syncthreads();
    // stage K tile (swizzled, direct-to-LDS)
    const u16* Kg = Kb + ((size_t)(b * CT + kv)) * CD + h * CDH;
    #pragma unroll
    for (int p = 0; p < 2; p++) {
      int idx = p * 256 + t;
      int row = idx >> 3, c = idx & 7;
      int cc = c ^ (row & 7);
      gload_lds16(Kg + (size_t)row * CD + cc * 8, Ks + (size_t)(p * 256 + (t & 192)) * 8);
    }
    // stage V transposed: Vs[d][key], two keys packed per dword write
    {
      int pair = t >> 3, d0 = (t & 7) * 8;
      const u16* Vg = Vb + ((size_t)(b * CT + kv + 2 * pair)) * CD + h * CDH + d0;
      uint4 va = *(const uint4*)Vg;
      uint4 vbq = *(const uint4*)(Vg + CD);
      u32* Vsd = (u32*)Vs;
      const u32* pa = (const u32*)&va;
      const u32* pb = (const u32*)&vbq;
      #pragma unroll
      for (int j = 0; j < 8; j++) {
        u32 a = pa[j >> 1], bb = pb[j >> 1];
        u32 lo = (j & 1) ? (a >> 16) : (a & 0xffffu);
        u32 hi = (j & 1) ? (bb & 0xffff0000u) : (bb << 16);
        Vsd[(d0 + j) * 36 + pair] = lo | hi;
      }
    }
    __syncthreads();

    // S = Q @ K^T (per wave: 16 q-rows x 64 keys)
    f32x4 s[4];
    #pragma unroll
    for (int jt = 0; jt < 4; jt++) {
      s[jt] = (f32x4){0.f, 0.f, 0.f, 0.f};
      int key = jt * 16 + m;
      #pragma unroll
      for (int kf = 0; kf < 2; kf++) {
        int ch = quad + kf * 4;
        bf16x8 kfr = *(const bf16x8*)&Ks[key * 64 + ((ch ^ (key & 7)) * 8)];
        s[jt] = __builtin_amdgcn_mfma_f32_16x16x32_bf16(qf[kf], kfr, s[jt], 0, 0, 0);
      }
    }

    // scale + mask + online softmax
    float p_v[4][4], curmax[4];
    #pragma unroll
    for (int r = 0; r < 4; r++) curmax[r] = -3e38f;
    #pragma unroll
    for (int jt = 0; jt < 4; jt++) {
      int keyg = kv + jt * 16 + m;
      float bias = mk[keyg] ? 0.f : -1e9f;
      #pragma unroll
      for (int r = 0; r < 4; r++) {
        float sv = s[jt][r] * 0.125f + bias;
        p_v[jt][r] = sv;
        curmax[r] = fmaxf(curmax[r], sv);
      }
    }
    #pragma unroll
    for (int r = 0; r < 4; r++)
      for (int off = 1; off < 16; off <<= 1)
        curmax[r] = fmaxf(curmax[r], __shfl_xor(curmax[r], off, 64));

    float alpha[4], rowsum[4];
    #pragma unroll
    for (int r = 0; r < 4; r++) {
      float mn = fmaxf(m_i[r], curmax[r]);
      alpha[r] = __expf(m_i[r] - mn);
      m_i[r] = mn;
      rowsum[r] = 0.f;
    }
    #pragma unroll
    for (int jt = 0; jt < 4; jt++)
      #pragma unroll
      for (int r = 0; r < 4; r++) {
        float pv = __expf(p_v[jt][r] - m_i[r]);
        p_v[jt][r] = pv;
        rowsum[r] += pv;
      }
    #pragma unroll
    for (int r = 0; r < 4; r++) {
      for (int off = 1; off < 16; off <<= 1)
        rowsum[r] += __shfl_xor(rowsum[r], off, 64);
      l_i[r] = l_i[r] * alpha[r] + rowsum[r];
      #pragma unroll
      for (int jt = 0; jt < 4; jt++) oacc[jt][r] *= alpha[r];
    }

    // P -> LDS (wave-private region; in-wave ds ordering, no barrier needed)
    #pragma unroll
    for (int jt = 0; jt < 4; jt++)
      #pragma unroll
      for (int r = 0; r < 4; r++)
        Ps[(w * 16 + quad * 4 + r) * 72 + jt * 16 + m] = f2b(p_v[jt][r]);

    // O += P @ V
    bf16x8 pf[2];
    #pragma unroll
    for (int kf = 0; kf < 2; kf++)
      pf[kf] = *(const bf16x8*)&Ps[(w * 16 + m) * 72 + kf * 32 + quad * 8];
    #pragma unroll
    for (int jt = 0; jt < 4; jt++) {
      #pragma unroll
      for (int kf = 0; kf < 2; kf++) {
        bf16x8 vf = *(const bf16x8*)&Vs[(jt * 16 + m) * 72 + kf * 32 + quad * 8];
        oacc[jt] = __builtin_amdgcn_mfma_f32_16x16x32_bf16(pf[kf], vf, oacc[jt], 0, 0, 0);
      }
    }
  }

  // epilogue: normalize and store bf16 [b][t][h*64+dh]
  #pragma unroll
  for (int r = 0; r < 4; r++) {
    float inv = 1.f / l_i[r];
    int tg = qt * 64 + w * 16 + quad * 4 + r;
    size_t base = ((size_t)(b * CT + tg)) * CD + h * CDH;
    #pragma unroll
    for (int jt = 0; jt < 4; jt++)
      Ob[base + jt * 16 + m] = f2b(oacc[jt][r] * inv);
  }
}

extern "C" void kernel_launch(void* const* d_in, const int* in_sizes, int n_in,
                              void* d_out, int out_size, void* d_ws, size_t ws_size,
                              hipStream_t stream) {
  const float* x  = (const float*)d_in[0];
  const int* mask = (const int*)d_in[1];
  const float* Wq = (const float*)d_in[2];
  const float* Wk = (const float*)d_in[3];
  const float* Wv = (const float*)d_in[4];
  const float* Wo = (const float*)d_in[5];
  float* out = (float*)d_out;

  u16* Xb   = (u16*)d_ws;                        // [4096][1024] bf16
  u16* Wqkv = Xb + (size_t)4096 * 1024;          // [3072][1024] = Wq^T|Wk^T|Wv^T
  u16* WoT  = Wqkv + (size_t)3072 * 1024;        // [1024][1024]
  u16* Qb   = WoT + (size_t)1024 * 1024;         // Q,K,V each [4096][1024]
  u16* Ob   = Qb + (size_t)3 * 4096 * 1024;      // attn out [4096][1024]

  cast_bf16_k<<<4096, 256, 0, stream>>>(x, Xb, 1048576);
  transpose_cast_k<<<dim3(32, 32), 256, 0, stream>>>(Wq, Wqkv);
  transpose_cast_k<<<dim3(32, 32), 256, 0, stream>>>(Wk, Wqkv + (size_t)1024 * 1024);
  transpose_cast_k<<<dim3(32, 32), 256, 0, stream>>>(Wv, Wqkv + (size_t)2 * 1024 * 1024);
  transpose_cast_k<<<dim3(32, 32), 256, 0, stream>>>(Wo, WoT);
  gemm_bt_k<u16><<<dim3(24, 32), 256, 0, stream>>>(Xb, Wqkv, Qb, 1024,
                                                   (size_t)4096 * 1024);
  attn_k<<<dim3(32, 16, 2), 256, 0, stream>>>(Qb, Qb + (size_t)4096 * 1024,
                                              Qb + (size_t)2 * 4096 * 1024, mask, Ob);
  gemm_bt_k<float><<<dim3(8, 32), 256, 0, stream>>>(Ob, WoT, out, 1024, 0);
}

// Round 2
// 235.627 us; speedup vs baseline: 1.2455x; 1.2455x over previous
//
#include <hip/hip_runtime.h>
#include <stdint.h>

typedef unsigned short u16;
typedef unsigned int u32;

constexpr int CB = 2, CT = 2048, CH = 16, CDH = 64, CD = 1024;

typedef __attribute__((ext_vector_type(8))) short bf16x8;
typedef __attribute__((ext_vector_type(4))) float f32x4;

typedef __attribute__((address_space(1))) const u32 as1_cu32;
typedef __attribute__((address_space(3))) u32 as3_u32;

__device__ __forceinline__ void gload_lds16(const void* g, void* l) {
  __builtin_amdgcn_global_load_lds((as1_cu32*)g, (as3_u32*)l, 16, 0, 0);
}

// fp32 -> bf16 round-to-nearest-even (finite inputs only)
__device__ __forceinline__ u16 f2b(float f) {
  u32 x = __float_as_uint(f);
  u32 r = (x + 0x7fffu + ((x >> 16) & 1u)) >> 16;
  return (u16)r;
}

#if __has_builtin(__builtin_amdgcn_cvt_pk_bf16_f32)
typedef __attribute__((ext_vector_type(2))) __bf16 v2bf;
__device__ __forceinline__ u32 pk2(float a, float b) {
  v2bf r = __builtin_amdgcn_cvt_pk_bf16_f32(a, b);
  union { v2bf v; u32 u; } cv; cv.v = r; return cv.u;
}
#else
__device__ __forceinline__ u32 pk2(float a, float b) {
  return (u32)f2b(a) | ((u32)f2b(b) << 16);
}
#endif

__device__ __forceinline__ void store_out(u16* p, float v) { *p = f2b(v); }
__device__ __forceinline__ void store_out(float* p, float v) { *p = v; }

// ---------------- cast x (fp32 -> bf16) ----------------
__global__ __launch_bounds__(256) void cast_bf16_k(const float* __restrict__ x,
                                                   u16* __restrict__ o, int n4) {
  int i = blockIdx.x * 256 + threadIdx.x;
  if (i < n4) {
    float4 v = ((const float4*)x)[i];
    ushort4 r;
    r.x = f2b(v.x); r.y = f2b(v.y); r.z = f2b(v.z); r.w = f2b(v.w);
    ((ushort4*)o)[i] = r;
  }
}

// ------------- transpose + cast W [K][N] fp32 -> Wt [N][K] bf16 -------------
__global__ __launch_bounds__(256) void transpose_cast_k(const float* __restrict__ W,
                                                        u16* __restrict__ Wt) {
  __shared__ float tile[32][33];
  int bx = blockIdx.x * 32, by = blockIdx.y * 32;
  int tx = threadIdx.x & 31, ty = threadIdx.x >> 5;  // 32 x 8
  #pragma unroll
  for (int i = ty; i < 32; i += 8) tile[i][tx] = W[(size_t)(by + i) * CD + bx + tx];
  __syncthreads();
  #pragma unroll
  for (int i = ty; i < 32; i += 8)
    Wt[(size_t)(bx + i) * CD + by + tx] = f2b(tile[tx][i]);
}

// ---------------- GEMM: C[M,1024-sub] = A[M,K]bf16 @ Bt[N,K]bf16^T ----------------
template <typename OT>
__global__ __launch_bounds__(256) void gemm_bt_k(const u16* __restrict__ A,
                                                 const u16* __restrict__ Bt,
                                                 OT* __restrict__ Cout,
                                                 int K, size_t subStride) {
  __shared__ __align__(16) u16 As[128 * 32];
  __shared__ __align__(16) u16 Bs[128 * 32];
  int t = threadIdx.x;
  int lane = t & 63, w = t >> 6;
  int m = lane & 15, quad = lane >> 4;
  int wrow = w >> 1, wcol = w & 1;
  int m0 = blockIdx.y * 128, n0 = blockIdx.x * 128;

  f32x4 acc[4][4];
  #pragma unroll
  for (int i = 0; i < 4; i++)
    #pragma unroll
    for (int j = 0; j < 4; j++) acc[i][j] = (f32x4){0.f, 0.f, 0.f, 0.f};

  for (int k0 = 0; k0 < K; k0 += 32) {
    __syncthreads();
    #pragma unroll
    for (int p = 0; p < 2; p++) {
      int idx = p * 256 + t;
      int row = idx >> 2, c = idx & 3;
      int cc = c ^ (row & 3);
      gload_lds16(A + (size_t)(m0 + row) * K + k0 + cc * 8,
                  As + (size_t)(p * 256 + (t & 192)) * 8);
      gload_lds16(Bt + (size_t)(n0 + row) * K + k0 + cc * 8,
                  Bs + (size_t)(p * 256 + (t & 192)) * 8);
    }
    __syncthreads();
    bf16x8 af[4], bfr[4];
    #pragma unroll
    for (int mt = 0; mt < 4; mt++) {
      int r = wrow * 64 + mt * 16 + m;
      af[mt] = *(const bf16x8*)&As[r * 32 + ((quad ^ (r & 3)) * 8)];
    }
    #pragma unroll
    for (int nt = 0; nt < 4; nt++) {
      int r = wcol * 64 + nt * 16 + m;
      bfr[nt] = *(const bf16x8*)&Bs[r * 32 + ((quad ^ (r & 3)) * 8)];
    }
    #pragma unroll
    for (int mt = 0; mt < 4; mt++)
      #pragma unroll
      for (int nt = 0; nt < 4; nt++)
        acc[mt][nt] = __builtin_amdgcn_mfma_f32_16x16x32_bf16(af[mt], bfr[nt],
                                                              acc[mt][nt], 0, 0, 0);
  }

  #pragma unroll
  for (int mt = 0; mt < 4; mt++) {
    #pragma unroll
    for (int nt = 0; nt < 4; nt++) {
      int c = n0 + wcol * 64 + nt * 16 + m;
      OT* outp = Cout + (size_t)(c >> 10) * subStride + (c & 1023);
      #pragma unroll
      for (int rr = 0; rr < 4; rr++) {
        int r = m0 + wrow * 64 + mt * 16 + quad * 4 + rr;
        store_out(outp + (size_t)r * CD, acc[mt][nt][rr]);
      }
    }
  }
}

// ---------------- flash attention (S^T form) ----------------
// grid (T/64, H, B), 128 threads = 2 waves; wave w owns q-rows [w*32, w*32+32).
// S^T = K·Q^T so each lane holds 4 consecutive keys -> b64 P writes, in-lane
// row sums (no per-iter shuffles). No max-subtraction (clamped exp).
__global__ __launch_bounds__(128) void attn_k(const u16* __restrict__ Qb,
                                              const u16* __restrict__ Kb,
                                              const u16* __restrict__ Vb,
                                              const int* __restrict__ mask,
                                              u16* __restrict__ Ob) {
  __shared__ __align__(16) u16 Qs[64 * 64];      // swizzled chunks
  __shared__ __align__(16) u16 Ks[64 * 64];      // swizzled chunks
  __shared__ __align__(16) u32 VsD[64 * 36];     // V^T dword (d,pr) at d*36 + (pr^(dg<<2))
  __shared__ __align__(16) u16 Ps[64 * 72];      // P [qrow][key], stride 72
  __shared__ u16 biasS[2048];                    // bf16 bias (0 or -1e9)
  __shared__ float Lf[64];

  int t = threadIdx.x, lane = t & 63, w = t >> 6;
  int m = lane & 15, quad = lane >> 4;
  int qt = blockIdx.x, h = blockIdx.y, b = blockIdx.z;
  const float scale = 0.125f;

  // stage Q (async, swizzled)
  const u16* Qg = Qb + ((size_t)(b * CT + qt * 64)) * CD + h * CDH;
  #pragma unroll
  for (int p = 0; p < 4; p++) {
    int idx = p * 128 + t;
    int row = idx >> 3, c = idx & 7;
    int cc = c ^ (row & 7);
    gload_lds16(Qg + (size_t)row * CD + cc * 8, Qs + (size_t)(p * 128 + (t & 64)) * 8);
  }

  // bias precompute + any-masked flag (barrier included)
  const int* mk = mask + b * CT;
  int localAny = 0;
  for (int i = t; i < CT; i += 128) {
    int mv = mk[i];
    biasS[i] = mv ? (u16)0 : f2b(-1.0e9f);
    localAny |= (mv == 0);
  }
  int anyM = __syncthreads_or(localAny);
  __syncthreads();

  // Q^T B-frags (hoisted): lane n=m holds Q[qrow][d=kf*32+quad*8+j]
  bf16x8 qbf[2][2];
  #pragma unroll
  for (int nt = 0; nt < 2; nt++) {
    int qrow = w * 32 + nt * 16 + m;
    #pragma unroll
    for (int kf = 0; kf < 2; kf++) {
      int ch = (4 * kf + quad) ^ (qrow & 7);
      qbf[nt][kf] = *(const bf16x8*)&Qs[qrow * 64 + ch * 8];
    }
  }

  f32x4 oacc[2][4];
  float lp[2] = {0.f, 0.f};
  #pragma unroll
  for (int nt = 0; nt < 2; nt++)
    #pragma unroll
    for (int j = 0; j < 4; j++) oacc[nt][j] = (f32x4){0.f, 0.f, 0.f, 0.f};

  for (int kv = 0; kv < CT; kv += 64) {
    __syncthreads();
    // stage K (async, swizzled)
    const u16* Kg = Kb + ((size_t)(b * CT + kv)) * CD + h * CDH;
    #pragma unroll
    for (int p = 0; p < 4; p++) {
      int idx = p * 128 + t;
      int row = idx >> 3, c = idx & 7;
      int cc = c ^ (row & 7);
      gload_lds16(Kg + (size_t)row * CD + cc * 8, Ks + (size_t)(p * 128 + (t & 64)) * 8);
    }
    // stage V^T (coalesced loads, v_perm pack, XOR-swizzled conflict-free writes)
    #pragma unroll
    for (int rep = 0; rep < 2; rep++) {
      int u = rep * 128 + t;
      int pr = u >> 3, dg = u & 7;
      const u16* Vg = Vb + ((size_t)(b * CT + kv + 2 * pr)) * CD + h * CDH + dg * 8;
      uint4 va = *(const uint4*)Vg;
      uint4 vb2 = *(const uint4*)(Vg + CD);
      const u32* pa = (const u32*)&va;
      const u32* pb = (const u32*)&vb2;
      u32* dst = VsD + 288 * dg + (pr ^ (dg << 2));
      #pragma unroll
      for (int j = 0; j < 8; j++) {
        u32 lo_dw = pa[j >> 1], hi_dw = pb[j >> 1];
        u32 pk = (j & 1) ? __builtin_amdgcn_perm(hi_dw, lo_dw, 0x07060302u)
                         : __builtin_amdgcn_perm(hi_dw, lo_dw, 0x05040100u);
        dst[j * 36] = pk;
      }
    }
    __syncthreads();

    // S^T = K·Q^T : D[key][qrow], col=qrow(m), row=key(quad*4+r)
    f32x4 s[2][4];
    #pragma unroll
    for (int jt = 0; jt < 4; jt++) {
      s[0][jt] = (f32x4){0.f, 0.f, 0.f, 0.f};
      s[1][jt] = (f32x4){0.f, 0.f, 0.f, 0.f};
      int key = jt * 16 + m;
      #pragma unroll
      for (int kf = 0; kf < 2; kf++) {
        int ch = (4 * kf + quad) ^ (key & 7);
        bf16x8 af = *(const bf16x8*)&Ks[key * 64 + ch * 8];
        s[0][jt] = __builtin_amdgcn_mfma_f32_16x16x32_bf16(af, qbf[0][kf], s[0][jt], 0, 0, 0);
        s[1][jt] = __builtin_amdgcn_mfma_f32_16x16x32_bf16(af, qbf[1][kf], s[1][jt], 0, 0, 0);
      }
    }

    // softmax (no max-shift; clamped) + P write (b64, conflict-free)
    #pragma unroll
    for (int nt = 0; nt < 2; nt++) {
      int qrow = w * 32 + nt * 16 + m;
      #pragma unroll
      for (int jt = 0; jt < 4; jt++) {
        float b0 = 0.f, b1 = 0.f, b2 = 0.f, b3 = 0.f;
        if (anyM) {
          uint2 bw = *(const uint2*)&biasS[kv + jt * 16 + quad * 4];
          b0 = __uint_as_float(bw.x << 16);
          b1 = __uint_as_float(bw.x & 0xffff0000u);
          b2 = __uint_as_float(bw.y << 16);
          b3 = __uint_as_float(bw.y & 0xffff0000u);
        }
        float p0 = __expf(fminf(fmaf(s[nt][jt][0], scale, b0), 30.f));
        float p1 = __expf(fminf(fmaf(s[nt][jt][1], scale, b1), 30.f));
        float p2 = __expf(fminf(fmaf(s[nt][jt][2], scale, b2), 30.f));
        float p3 = __expf(fminf(fmaf(s[nt][jt][3], scale, b3), 30.f));
        lp[nt] += (p0 + p1) + (p2 + p3);
        uint2 pw;
        pw.x = pk2(p0, p1);
        pw.y = pk2(p2, p3);
        *(uint2*)&Ps[qrow * 72 + jt * 16 + quad * 4] = pw;
      }
    }

    // O += P·V  (A=P qrow-major, B=V^T)
    bf16x8 pf[2][2];
    #pragma unroll
    for (int nt = 0; nt < 2; nt++)
      #pragma unroll
      for (int kf2 = 0; kf2 < 2; kf2++)
        pf[nt][kf2] = *(const bf16x8*)&Ps[(w * 32 + nt * 16 + m) * 72 + kf2 * 32 + quad * 8];
    #pragma unroll
    for (int jt2 = 0; jt2 < 4; jt2++) {
      int row = jt2 * 16 + m;
      int X = ((row >> 3) & 7) << 2;
      #pragma unroll
      for (int kf2 = 0; kf2 < 2; kf2++) {
        const u32* vp = VsD + row * 36 + ((16 * kf2 + 4 * quad) ^ X);
        bf16x8 vf = *(const bf16x8*)vp;
        oacc[0][jt2] = __builtin_amdgcn_mfma_f32_16x16x32_bf16(pf[0][kf2], vf, oacc[0][jt2], 0, 0, 0);
        oacc[1][jt2] = __builtin_amdgcn_mfma_f32_16x16x32_bf16(pf[1][kf2], vf, oacc[1][jt2], 0, 0, 0);
      }
    }
  }

  // final l reduction (across quads) + normalize + store
  #pragma unroll
  for (int nt = 0; nt < 2; nt++) {
    float l = lp[nt];
    l += __shfl_xor(l, 16, 64);
    l += __shfl_xor(l, 32, 64);
    if (lane < 16) Lf[w * 32 + nt * 16 + lane] = l;
  }
  __syncthreads();
  #pragma unroll
  for (int nt = 0; nt < 2; nt++) {
    #pragma unroll
    for (int r = 0; r < 4; r++) {
      float linv = 1.f / Lf[w * 32 + nt * 16 + quad * 4 + r];
      int tg = qt * 64 + w * 32 + nt * 16 + quad * 4 + r;
      size_t base = ((size_t)(b * CT + tg)) * CD + h * CDH;
      #pragma unroll
      for (int jt2 = 0; jt2 < 4; jt2++)
        Ob[base + jt2 * 16 + m] = f2b(oacc[nt][jt2][r] * linv);
    }
  }
}

extern "C" void kernel_launch(void* const* d_in, const int* in_sizes, int n_in,
                              void* d_out, int out_size, void* d_ws, size_t ws_size,
                              hipStream_t stream) {
  const float* x  = (const float*)d_in[0];
  const int* mask = (const int*)d_in[1];
  const float* Wq = (const float*)d_in[2];
  const float* Wk = (const float*)d_in[3];
  const float* Wv = (const float*)d_in[4];
  const float* Wo = (const float*)d_in[5];
  float* out = (float*)d_out;

  u16* Xb   = (u16*)d_ws;                        // [4096][1024] bf16
  u16* Wqkv = Xb + (size_t)4096 * 1024;          // [3072][1024] = Wq^T|Wk^T|Wv^T
  u16* WoT  = Wqkv + (size_t)3072 * 1024;        // [1024][1024]
  u16* Qb   = WoT + (size_t)1024 * 1024;         // Q,K,V each [4096][1024]
  u16* Ob   = Qb + (size_t)3 * 4096 * 1024;      // attn out [4096][1024]

  cast_bf16_k<<<4096, 256, 0, stream>>>(x, Xb, 1048576);
  transpose_cast_k<<<dim3(32, 32), 256, 0, stream>>>(Wq, Wqkv);
  transpose_cast_k<<<dim3(32, 32), 256, 0, stream>>>(Wk, Wqkv + (size_t)1024 * 1024);
  transpose_cast_k<<<dim3(32, 32), 256, 0, stream>>>(Wv, Wqkv + (size_t)2 * 1024 * 1024);
  transpose_cast_k<<<dim3(32, 32), 256, 0, stream>>>(Wo, WoT);
  gemm_bt_k<u16><<<dim3(24, 32), 256, 0, stream>>>(Xb, Wqkv, Qb, 1024,
                                                   (size_t)4096 * 1024);
  attn_k<<<dim3(32, 16, 2), 128, 0, stream>>>(Qb, Qb + (size_t)4096 * 1024,
                                              Qb + (size_t)2 * 4096 * 1024, mask, Ob);
  gemm_bt_k<float><<<dim3(8, 32), 256, 0, stream>>>(Ob, WoT, out, 1024, 0);
}

// Round 3
// 220.312 us; speedup vs baseline: 1.3321x; 1.0695x over previous
//
#include <hip/hip_runtime.h>
#include <stdint.h>

typedef unsigned short u16;
typedef unsigned int u32;

constexpr int CB = 2, CT = 2048, CH = 16, CDH = 64, CD = 1024;

typedef __attribute__((ext_vector_type(8))) short bf16x8;
typedef __attribute__((ext_vector_type(4))) float f32x4;
typedef __attribute__((ext_vector_type(16))) float f32x16;

typedef __attribute__((address_space(1))) const u32 as1_cu32;
typedef __attribute__((address_space(3))) u32 as3_u32;

__device__ __forceinline__ void gload_lds16(const void* g, void* l) {
  __builtin_amdgcn_global_load_lds((as1_cu32*)g, (as3_u32*)l, 16, 0, 0);
}

// fp32 -> bf16 round-to-nearest-even (finite inputs only)
__device__ __forceinline__ u16 f2b(float f) {
  u32 x = __float_as_uint(f);
  u32 r = (x + 0x7fffu + ((x >> 16) & 1u)) >> 16;
  return (u16)r;
}

#if __has_builtin(__builtin_amdgcn_cvt_pk_bf16_f32)
typedef __attribute__((ext_vector_type(2))) __bf16 v2bf;
__device__ __forceinline__ u32 pk2(float a, float b) {
  v2bf r = __builtin_amdgcn_cvt_pk_bf16_f32(a, b);
  union { v2bf v; u32 u; } cv; cv.v = r; return cv.u;
}
#else
__device__ __forceinline__ u32 pk2(float a, float b) {
  return (u32)f2b(a) | ((u32)f2b(b) << 16);
}
#endif

__device__ __forceinline__ float b2f(u32 lo16) { return __uint_as_float(lo16 << 16); }

__device__ __forceinline__ void store_out(u16* p, float v) { *p = f2b(v); }
__device__ __forceinline__ void store_out(float* p, float v) { *p = v; }

// half-swap: a' = {a.lo32lanes, b.lo32lanes}, b' = {a.hi, b.hi}
__device__ __forceinline__ void plswap(u32& a, u32& b, int hf) {
  u32 ta = (u32)__shfl_xor((int)a, 32, 64);
  u32 tb = (u32)__shfl_xor((int)b, 32, 64);
  u32 na = hf ? tb : a;
  u32 nb = hf ? b : ta;
  a = na; b = nb;
}

// ---------------- fused prep: cast x + transpose/cast 4 weight mats ----------------
__global__ __launch_bounds__(256) void prep_k(const float* __restrict__ x,
                                              const float* __restrict__ Wq,
                                              const float* __restrict__ Wk,
                                              const float* __restrict__ Wv,
                                              const float* __restrict__ Wo,
                                              u16* __restrict__ Xb,
                                              u16* __restrict__ Wt) {
  __shared__ float tile[32][33];
  int bid = blockIdx.x, t = threadIdx.x;
  if (bid < 4096) {
    int i = bid * 256 + t;
    float4 v = ((const float4*)x)[i];
    ushort4 r;
    r.x = f2b(v.x); r.y = f2b(v.y); r.z = f2b(v.z); r.w = f2b(v.w);
    ((ushort4*)Xb)[i] = r;
  } else {
    int tid2 = bid - 4096;
    int mat = tid2 >> 10, b2 = tid2 & 1023;
    const float* W = (mat == 0) ? Wq : (mat == 1) ? Wk : (mat == 2) ? Wv : Wo;
    u16* dst = Wt + (size_t)mat * 1048576;
    int bx = (b2 & 31) * 32, by = (b2 >> 5) * 32;
    int tx = t & 31, ty = t >> 5;
    #pragma unroll
    for (int i = ty; i < 32; i += 8) tile[i][tx] = W[(size_t)(by + i) * CD + bx + tx];
    __syncthreads();
    #pragma unroll
    for (int i = ty; i < 32; i += 8)
      dst[(size_t)(bx + i) * CD + by + tx] = f2b(tile[tx][i]);
  }
}

// ---------------- GEMM: C[M,1024-sub] = A[M,K]bf16 @ Bt[N,K]bf16^T ----------------
template <typename OT>
__global__ __launch_bounds__(256) void gemm_bt_k(const u16* __restrict__ A,
                                                 const u16* __restrict__ Bt,
                                                 OT* __restrict__ Cout,
                                                 int K, size_t subStride) {
  __shared__ __align__(16) u16 As[128 * 32];
  __shared__ __align__(16) u16 Bs[128 * 32];
  int t = threadIdx.x;
  int lane = t & 63, w = t >> 6;
  int m = lane & 15, quad = lane >> 4;
  int wrow = w >> 1, wcol = w & 1;
  int m0 = blockIdx.y * 128, n0 = blockIdx.x * 128;

  f32x4 acc[4][4];
  #pragma unroll
  for (int i = 0; i < 4; i++)
    #pragma unroll
    for (int j = 0; j < 4; j++) acc[i][j] = (f32x4){0.f, 0.f, 0.f, 0.f};

  for (int k0 = 0; k0 < K; k0 += 32) {
    __syncthreads();
    #pragma unroll
    for (int p = 0; p < 2; p++) {
      int idx = p * 256 + t;
      int row = idx >> 2, c = idx & 3;
      int cc = c ^ (row & 3);
      gload_lds16(A + (size_t)(m0 + row) * K + k0 + cc * 8,
                  As + (size_t)(p * 256 + (t & 192)) * 8);
      gload_lds16(Bt + (size_t)(n0 + row) * K + k0 + cc * 8,
                  Bs + (size_t)(p * 256 + (t & 192)) * 8);
    }
    __syncthreads();
    bf16x8 af[4], bfr[4];
    #pragma unroll
    for (int mt = 0; mt < 4; mt++) {
      int r = wrow * 64 + mt * 16 + m;
      af[mt] = *(const bf16x8*)&As[r * 32 + ((quad ^ (r & 3)) * 8)];
    }
    #pragma unroll
    for (int nt = 0; nt < 4; nt++) {
      int r = wcol * 64 + nt * 16 + m;
      bfr[nt] = *(const bf16x8*)&Bs[r * 32 + ((quad ^ (r & 3)) * 8)];
    }
    #pragma unroll
    for (int mt = 0; mt < 4; mt++)
      #pragma unroll
      for (int nt = 0; nt < 4; nt++)
        acc[mt][nt] = __builtin_amdgcn_mfma_f32_16x16x32_bf16(af[mt], bfr[nt],
                                                              acc[mt][nt], 0, 0, 0);
  }

  #pragma unroll
  for (int mt = 0; mt < 4; mt++) {
    #pragma unroll
    for (int nt = 0; nt < 4; nt++) {
      int c = n0 + wcol * 64 + nt * 16 + m;
      OT* outp = Cout + (size_t)(c >> 10) * subStride + (c & 1023);
      #pragma unroll
      for (int rr = 0; rr < 4; rr++) {
        int r = m0 + wrow * 64 + mt * 16 + quad * 4 + rr;
        store_out(outp + (size_t)r * CD, acc[mt][nt][rr]);
      }
    }
  }
}

// ---------------- flash attention, 32x32 MFMA, kv-split, no P-LDS ----------------
// grid (T/128, H, B*2): z = b + 2*half. 256 threads = 4 waves; wave w owns
// q-rows [w*32, w*32+32). S^T = K*Q^T (col=qrow), O^T = V^T*P^T; P frags built
// in-register via half-swaps. Partials (bf16 O/l per half) merged by combine_k.
__global__ __launch_bounds__(256, 4) void attn_k(const u16* __restrict__ Qb,
                                                 const u16* __restrict__ Kb,
                                                 const u16* __restrict__ Vb,
                                                 const int* __restrict__ mask,
                                                 u16* __restrict__ Opart,
                                                 float* __restrict__ Lpart) {
  __shared__ __align__(16) u16 Ks[64 * 64];   // swizzled 16B chunks
  __shared__ __align__(16) u32 VsD[64 * 36];  // V^T dword (d,pr) at d*36 + (pr^((d>>3)<<2))

  int t = threadIdx.x, lane = t & 63, w = t >> 6;
  int c32 = lane & 31, hf = lane >> 5;
  int qt = blockIdx.x, head = blockIdx.y;
  int b = blockIdx.z & 1, half = blockIdx.z >> 1;
  int kv0 = half * 1024;
  int gid = (b * 16 + head) * 16 + qt;

  // Q fragments direct from global (one-time): B-layout col=qrow, k=hf*8+j
  const u16* Qg = Qb + ((size_t)(b * CT + qt * 128 + w * 32 + c32)) * CD + head * CDH;
  bf16x8 qbf[4];
  #pragma unroll
  for (int kc = 0; kc < 4; kc++)
    qbf[kc] = *(const bf16x8*)(Qg + kc * 16 + hf * 8);

  // mask scan over this half
  const int* mk = mask + b * CT + kv0;
  int localAny = 0;
  for (int i = t; i < 1024; i += 256) localAny |= (mk[i] == 0);
  int anyM = __syncthreads_or(localAny);

  f32x16 oacc[2];
  #pragma unroll
  for (int dt = 0; dt < 2; dt++)
    #pragma unroll
    for (int r = 0; r < 16; r++) oacc[dt][r] = 0.f;
  float lp = 0.f;

  const u16* Kg0 = Kb + ((size_t)(b * CT + kv0)) * CD + head * CDH;
  const u16* Vg0 = Vb + ((size_t)(b * CT + kv0)) * CD + head * CDH;

  // V prefetch (iter 0)
  int vpr = t >> 3, vdg = t & 7;
  const u16* VgT = Vg0 + (size_t)(2 * vpr) * CD + vdg * 8;
  uint4 va = *(const uint4*)VgT;
  uint4 vb2 = *(const uint4*)(VgT + CD);

  for (int kv = 0; kv < 1024; kv += 64) {
    __syncthreads();
    // stage K (async DMA, swizzled)
    #pragma unroll
    for (int p = 0; p < 2; p++) {
      int idx = p * 256 + t;
      int row = idx >> 3, cc = (idx & 7) ^ (row & 7);
      gload_lds16(Kg0 + (size_t)(kv + row) * CD + cc * 8,
                  Ks + (size_t)(p * 256 + (t & 192)) * 8);
    }
    // stage V^T from prefetched regs (2-way-free swizzled writes)
    {
      const u32* pa = (const u32*)&va;
      const u32* pb = (const u32*)&vb2;
      u32* dst = VsD + (size_t)vdg * 288 + (vpr ^ (vdg << 2));
      #pragma unroll
      for (int j = 0; j < 8; j++) {
        u32 lo_dw = pa[j >> 1], hi_dw = pb[j >> 1];
        u32 pk = (j & 1) ? __builtin_amdgcn_perm(hi_dw, lo_dw, 0x07060302u)
                         : __builtin_amdgcn_perm(hi_dw, lo_dw, 0x05040100u);
        dst[j * 36] = pk;
      }
    }
    __syncthreads();
    // prefetch next V tile
    if (kv + 64 < 1024) {
      VgT = Vg0 + (size_t)(kv + 64 + 2 * vpr) * CD + vdg * 8;
      va = *(const uint4*)VgT;
      vb2 = *(const uint4*)(VgT + CD);
    }

    #pragma unroll
    for (int kt = 0; kt < 2; kt++) {
      // S^T tile: 32 keys x 32 qrows, K-dim 64
      f32x16 sv;
      #pragma unroll
      for (int r = 0; r < 16; r++) sv[r] = 0.f;
      int key = kt * 32 + c32;
      #pragma unroll
      for (int kc = 0; kc < 4; kc++) {
        int ch = kc * 2 + hf;
        bf16x8 af = *(const bf16x8*)&Ks[key * 64 + ((ch ^ (key & 7)) * 8)];
        sv = __builtin_amdgcn_mfma_f32_32x32x16_bf16(af, qbf[kc], sv, 0, 0, 0);
      }
      // softmax (no max-shift) + pack
      float pv[16];
      #pragma unroll
      for (int r = 0; r < 16; r++) {
        float xs = sv[r] * 0.125f;
        if (anyM) {
          int mi = kv + kt * 32 + (r & 3) + 8 * (r >> 2) + 4 * hf;
          xs += mk[mi] ? 0.f : -1.0e9f;
        }
        pv[r] = __expf(fminf(xs, 30.f));
        lp += pv[r];
      }
      u32 pk[8];
      #pragma unroll
      for (int i = 0; i < 8; i++) pk[i] = pk2(pv[2 * i], pv[2 * i + 1]);
      // per 16-key chunk: build P B-frag via half-swaps, then PV MFMAs
      #pragma unroll
      for (int c = 0; c < 2; c++) {
        u32 d0 = pk[4 * c + 0], d2 = pk[4 * c + 2];
        u32 d1 = pk[4 * c + 1], d3 = pk[4 * c + 3];
        plswap(d0, d2, hf);
        plswap(d1, d3, hf);
        union { u32 u[4]; bf16x8 v; } pf;
        pf.u[0] = d0; pf.u[1] = d1; pf.u[2] = d2; pf.u[3] = d3;
        int prb = kt * 16 + c * 8 + hf * 4;
        #pragma unroll
        for (int dt = 0; dt < 2; dt++) {
          int d = dt * 32 + c32;
          const u32* vp = VsD + d * 36 + (prb ^ ((d >> 3) << 2));
          bf16x8 vf = *(const bf16x8*)vp;
          oacc[dt] = __builtin_amdgcn_mfma_f32_32x32x16_bf16(vf, pf.v, oacc[dt], 0, 0, 0);
        }
      }
    }
  }

  // epilogue: reduce l across halves (in-lane rows), normalize, store partial
  float lT = lp + __shfl_xor(lp, 32, 64);
  float linv = 1.f / lT;
  u16* Op = Opart + ((size_t)(half * 512 + gid) * 128 + w * 32 + c32) * 64;
  #pragma unroll
  for (int dt = 0; dt < 2; dt++) {
    #pragma unroll
    for (int g = 0; g < 4; g++) {
      float o0 = oacc[dt][4 * g + 0] * linv, o1 = oacc[dt][4 * g + 1] * linv;
      float o2 = oacc[dt][4 * g + 2] * linv, o3 = oacc[dt][4 * g + 3] * linv;
      uint2 pw;
      pw.x = pk2(o0, o1);
      pw.y = pk2(o2, o3);
      *(uint2*)(Op + dt * 32 + 8 * g + 4 * hf) = pw;
    }
  }
  if (lane < 32) Lpart[(size_t)(half * 512 + gid) * 128 + w * 32 + lane] = lT;
}

// ---------------- combine kv-split partials ----------------
__global__ __launch_bounds__(256) void combine_k(const u16* __restrict__ Opart,
                                                 const float* __restrict__ Lpart,
                                                 u16* __restrict__ Ob) {
  int fid = blockIdx.x * 256 + threadIdx.x;  // 1M threads, 4 elems each
  int gid = fid >> 11;
  int rem = fid & 2047;
  int r = rem >> 4, d = (rem & 15) * 4;
  int b = gid >> 8, head = (gid >> 4) & 15, qt = gid & 15;
  size_t i0 = ((size_t)gid * 128 + r) * 64 + d;
  size_t i1 = ((size_t)(512 + gid) * 128 + r) * 64 + d;
  uint2 A = *(const uint2*)(Opart + i0);
  uint2 Bv = *(const uint2*)(Opart + i1);
  float la = Lpart[gid * 128 + r], lb = Lpart[(512 + gid) * 128 + r];
  float inv = 1.f / (la + lb);
  float wa = la * inv, wb = lb * inv;
  float o0 = wa * b2f(A.x & 0xffffu) + wb * b2f(Bv.x & 0xffffu);
  float o1 = wa * b2f(A.x >> 16) + wb * b2f(Bv.x >> 16);
  float o2 = wa * b2f(A.y & 0xffffu) + wb * b2f(Bv.y & 0xffffu);
  float o3 = wa * b2f(A.y >> 16) + wb * b2f(Bv.y >> 16);
  uint2 pw;
  pw.x = pk2(o0, o1);
  pw.y = pk2(o2, o3);
  size_t trow = (size_t)b * CT + qt * 128 + r;
  *(uint2*)(Ob + trow * CD + head * CDH + d) = pw;
}

extern "C" void kernel_launch(void* const* d_in, const int* in_sizes, int n_in,
                              void* d_out, int out_size, void* d_ws, size_t ws_size,
                              hipStream_t stream) {
  const float* x  = (const float*)d_in[0];
  const int* mask = (const int*)d_in[1];
  const float* Wq = (const float*)d_in[2];
  const float* Wk = (const float*)d_in[3];
  const float* Wv = (const float*)d_in[4];
  const float* Wo = (const float*)d_in[5];
  float* out = (float*)d_out;

  u16* Xb    = (u16*)d_ws;                         // [4096][1024]
  u16* Wqkv  = Xb + (size_t)4096 * 1024;           // Wq^T|Wk^T|Wv^T|Wo^T [4096][1024]
  u16* WoT   = Wqkv + (size_t)3072 * 1024;
  u16* Qb    = Wqkv + (size_t)4096 * 1024;         // Q,K,V each [4096][1024]
  u16* Ob    = Qb + (size_t)3 * 4096 * 1024;       // attn out [4096][1024]
  u16* Opart = Ob + (size_t)4096 * 1024;           // [2*512][128][64] bf16
  float* Lpart = (float*)(Opart + (size_t)2 * 512 * 128 * 64);  // [2*512][128]

  prep_k<<<8192, 256, 0, stream>>>(x, Wq, Wk, Wv, Wo, Xb, Wqkv);
  gemm_bt_k<u16><<<dim3(24, 32), 256, 0, stream>>>(Xb, Wqkv, Qb, 1024,
                                                   (size_t)4096 * 1024);
  attn_k<<<dim3(16, 16, 4), 256, 0, stream>>>(Qb, Qb + (size_t)4096 * 1024,
                                              Qb + (size_t)2 * 4096 * 1024, mask,
                                              Opart, Lpart);
  combine_k<<<4096, 256, 0, stream>>>(Opart, Lpart, Ob);
  gemm_bt_k<float><<<dim3(8, 32), 256, 0, stream>>>(Ob, WoT, out, 1024, 0);
}

// Round 4
// 218.773 us; speedup vs baseline: 1.3415x; 1.0070x over previous
//
#include <hip/hip_runtime.h>
#include <stdint.h>

typedef unsigned short u16;
typedef unsigned int u32;

constexpr int CB = 2, CT = 2048, CH = 16, CDH = 64, CD = 1024;

typedef __attribute__((ext_vector_type(8))) short bf16x8;
typedef __attribute__((ext_vector_type(4))) float f32x4;
typedef __attribute__((ext_vector_type(16))) float f32x16;

typedef __attribute__((address_space(1))) const u32 as1_cu32;
typedef __attribute__((address_space(3))) u32 as3_u32;

__device__ __forceinline__ void gload_lds16(const void* g, void* l) {
  __builtin_amdgcn_global_load_lds((as1_cu32*)g, (as3_u32*)l, 16, 0, 0);
}

// fp32 -> bf16 round-to-nearest-even (finite inputs only)
__device__ __forceinline__ u16 f2b(float f) {
  u32 x = __float_as_uint(f);
  u32 r = (x + 0x7fffu + ((x >> 16) & 1u)) >> 16;
  return (u16)r;
}

#if __has_builtin(__builtin_amdgcn_cvt_pk_bf16_f32)
typedef __attribute__((ext_vector_type(2))) __bf16 v2bf;
__device__ __forceinline__ u32 pk2(float a, float b) {
  v2bf r = __builtin_amdgcn_cvt_pk_bf16_f32(a, b);
  union { v2bf v; u32 u; } cv; cv.v = r; return cv.u;
}
#else
__device__ __forceinline__ u32 pk2(float a, float b) {
  return (u32)f2b(a) | ((u32)f2b(b) << 16);
}
#endif

__device__ __forceinline__ float b2f(u32 lo16) { return __uint_as_float(lo16 << 16); }

__device__ __forceinline__ void store_out(u16* p, float v) { *p = f2b(v); }
__device__ __forceinline__ void store_out(float* p, float v) { *p = v; }

// half-swap: a' = {a.lo32lanes, b.lo32lanes}, b' = {a.hi, b.hi}
#if __has_builtin(__builtin_amdgcn_permlane32_swap)
__device__ __forceinline__ void plswap(u32& a, u32& b, int) {
  auto r = __builtin_amdgcn_permlane32_swap(a, b, false, false);
  a = (u32)r[0]; b = (u32)r[1];
}
#else
__device__ __forceinline__ void plswap(u32& a, u32& b, int hf) {
  u32 ta = (u32)__shfl_xor((int)a, 32, 64);
  u32 tb = (u32)__shfl_xor((int)b, 32, 64);
  u32 na = hf ? tb : a;
  u32 nb = hf ? b : ta;
  a = na; b = nb;
}
#endif

// ---------------- fused prep: cast x + transpose/cast 4 weight mats ----------------
__global__ __launch_bounds__(256) void prep_k(const float* __restrict__ x,
                                              const float* __restrict__ Wq,
                                              const float* __restrict__ Wk,
                                              const float* __restrict__ Wv,
                                              const float* __restrict__ Wo,
                                              u16* __restrict__ Xb,
                                              u16* __restrict__ Wt) {
  __shared__ float tile[32][33];
  int bid = blockIdx.x, t = threadIdx.x;
  if (bid < 4096) {
    int i = bid * 256 + t;
    float4 v = ((const float4*)x)[i];
    ushort4 r;
    r.x = f2b(v.x); r.y = f2b(v.y); r.z = f2b(v.z); r.w = f2b(v.w);
    ((ushort4*)Xb)[i] = r;
  } else {
    int tid2 = bid - 4096;
    int mat = tid2 >> 10, b2 = tid2 & 1023;
    const float* W = (mat == 0) ? Wq : (mat == 1) ? Wk : (mat == 2) ? Wv : Wo;
    u16* dst = Wt + (size_t)mat * 1048576;
    int bx = (b2 & 31) * 32, by = (b2 >> 5) * 32;
    int tx = t & 31, ty = t >> 5;
    #pragma unroll
    for (int i = ty; i < 32; i += 8) tile[i][tx] = W[(size_t)(by + i) * CD + bx + tx];
    __syncthreads();
    #pragma unroll
    for (int i = ty; i < 32; i += 8)
      dst[(size_t)(bx + i) * CD + by + tx] = f2b(tile[tx][i]);
  }
}

// ---------------- GEMM 128x128: C[M,1024-sub] = A[M,K] @ Bt[N,K]^T ----------------
template <typename OT>
__global__ __launch_bounds__(256) void gemm_bt_k(const u16* __restrict__ A,
                                                 const u16* __restrict__ Bt,
                                                 OT* __restrict__ Cout,
                                                 int K, size_t subStride) {
  __shared__ __align__(16) u16 As[128 * 32];
  __shared__ __align__(16) u16 Bs[128 * 32];
  int t = threadIdx.x;
  int lane = t & 63, w = t >> 6;
  int m = lane & 15, quad = lane >> 4;
  int wrow = w >> 1, wcol = w & 1;
  int m0 = blockIdx.y * 128, n0 = blockIdx.x * 128;

  f32x4 acc[4][4];
  #pragma unroll
  for (int i = 0; i < 4; i++)
    #pragma unroll
    for (int j = 0; j < 4; j++) acc[i][j] = (f32x4){0.f, 0.f, 0.f, 0.f};

  for (int k0 = 0; k0 < K; k0 += 32) {
    __syncthreads();
    #pragma unroll
    for (int p = 0; p < 2; p++) {
      int idx = p * 256 + t;
      int row = idx >> 2, c = idx & 3;
      int cc = c ^ (row & 3);
      gload_lds16(A + (size_t)(m0 + row) * K + k0 + cc * 8,
                  As + (size_t)(p * 256 + (t & 192)) * 8);
      gload_lds16(Bt + (size_t)(n0 + row) * K + k0 + cc * 8,
                  Bs + (size_t)(p * 256 + (t & 192)) * 8);
    }
    __syncthreads();
    bf16x8 af[4], bfr[4];
    #pragma unroll
    for (int mt = 0; mt < 4; mt++) {
      int r = wrow * 64 + mt * 16 + m;
      af[mt] = *(const bf16x8*)&As[r * 32 + ((quad ^ (r & 3)) * 8)];
    }
    #pragma unroll
    for (int nt = 0; nt < 4; nt++) {
      int r = wcol * 64 + nt * 16 + m;
      bfr[nt] = *(const bf16x8*)&Bs[r * 32 + ((quad ^ (r & 3)) * 8)];
    }
    #pragma unroll
    for (int mt = 0; mt < 4; mt++)
      #pragma unroll
      for (int nt = 0; nt < 4; nt++)
        acc[mt][nt] = __builtin_amdgcn_mfma_f32_16x16x32_bf16(af[mt], bfr[nt],
                                                              acc[mt][nt], 0, 0, 0);
  }

  #pragma unroll
  for (int mt = 0; mt < 4; mt++) {
    #pragma unroll
    for (int nt = 0; nt < 4; nt++) {
      int c = n0 + wcol * 64 + nt * 16 + m;
      OT* outp = Cout + (size_t)(c >> 10) * subStride + (c & 1023);
      #pragma unroll
      for (int rr = 0; rr < 4; rr++) {
        int r = m0 + wrow * 64 + mt * 16 + quad * 4 + rr;
        store_out(outp + (size_t)r * CD, acc[mt][nt][rr]);
      }
    }
  }
}

// ---------------- GEMM 128x64 (out-proj): more blocks for occupancy ----------------
__global__ __launch_bounds__(256) void gemm_bt64_k(const u16* __restrict__ A,
                                                   const u16* __restrict__ Bt,
                                                   float* __restrict__ Cout, int K) {
  __shared__ __align__(16) u16 As[128 * 32];
  __shared__ __align__(16) u16 Bs[64 * 32];
  int t = threadIdx.x;
  int lane = t & 63, w = t >> 6;
  int m = lane & 15, quad = lane >> 4;
  int wrow = w >> 1, wcol = w & 1;
  int m0 = blockIdx.y * 128, n0 = blockIdx.x * 64;

  f32x4 acc[4][2];
  #pragma unroll
  for (int i = 0; i < 4; i++)
    #pragma unroll
    for (int j = 0; j < 2; j++) acc[i][j] = (f32x4){0.f, 0.f, 0.f, 0.f};

  for (int k0 = 0; k0 < K; k0 += 32) {
    __syncthreads();
    #pragma unroll
    for (int p = 0; p < 2; p++) {
      int idx = p * 256 + t;
      int row = idx >> 2, cc = (idx & 3) ^ (row & 3);
      gload_lds16(A + (size_t)(m0 + row) * K + k0 + cc * 8,
                  As + (size_t)(p * 256 + (t & 192)) * 8);
    }
    {
      int row = t >> 2, cc = (t & 3) ^ (row & 3);
      gload_lds16(Bt + (size_t)(n0 + row) * K + k0 + cc * 8,
                  Bs + (size_t)(t & 192) * 8);
    }
    __syncthreads();
    bf16x8 af[4], bfr[2];
    #pragma unroll
    for (int mt = 0; mt < 4; mt++) {
      int r = wrow * 64 + mt * 16 + m;
      af[mt] = *(const bf16x8*)&As[r * 32 + ((quad ^ (r & 3)) * 8)];
    }
    #pragma unroll
    for (int nt = 0; nt < 2; nt++) {
      int r = wcol * 32 + nt * 16 + m;
      bfr[nt] = *(const bf16x8*)&Bs[r * 32 + ((quad ^ (r & 3)) * 8)];
    }
    #pragma unroll
    for (int mt = 0; mt < 4; mt++)
      #pragma unroll
      for (int nt = 0; nt < 2; nt++)
        acc[mt][nt] = __builtin_amdgcn_mfma_f32_16x16x32_bf16(af[mt], bfr[nt],
                                                              acc[mt][nt], 0, 0, 0);
  }

  #pragma unroll
  for (int mt = 0; mt < 4; mt++) {
    #pragma unroll
    for (int nt = 0; nt < 2; nt++) {
      int c = n0 + wcol * 32 + nt * 16 + m;
      #pragma unroll
      for (int rr = 0; rr < 4; rr++) {
        int r = m0 + wrow * 64 + mt * 16 + quad * 4 + rr;
        Cout[(size_t)r * CD + c] = acc[mt][nt][rr];
      }
    }
  }
}

// ---------------- flash attention: 64 qrows/wave, permlane P-swap, kv-split ----------------
// grid (16, H, B*2). 128 threads = 2 waves; wave w owns qrows [w*64, w*64+64)
// as 2 groups of 32. S^T = K*Q^T (col=qrow), O^T = V^T*P^T; P frags in-register.
__global__ __launch_bounds__(128, 2) void attn_k(const u16* __restrict__ Qb,
                                                 const u16* __restrict__ Kb,
                                                 const u16* __restrict__ Vb,
                                                 const int* __restrict__ mask,
                                                 u16* __restrict__ Opart,
                                                 float* __restrict__ Lpart) {
  __shared__ __align__(16) u16 Ks[64 * 64];   // swizzled 16B chunks
  __shared__ __align__(16) u32 VsD[64 * 36];  // V^T dword (d,pr) at d*36 + (pr^((d>>3)<<2))

  int t = threadIdx.x, lane = t & 63, w = t >> 6;
  int c32 = lane & 31, hf = lane >> 5;
  int qt = blockIdx.x, head = blockIdx.y;
  int b = blockIdx.z & 1, half = blockIdx.z >> 1;
  int kv0 = half * 1024;
  int gid = (b * 16 + head) * 16 + qt;

  // Q fragments direct from global: B-layout col=qrow, k=hf*8+j (2 qg x 4 kc)
  bf16x8 qbf[2][4];
  #pragma unroll
  for (int qg = 0; qg < 2; qg++) {
    const u16* Qg = Qb + ((size_t)(b * CT + qt * 128 + w * 64 + qg * 32 + c32)) * CD + head * CDH;
    #pragma unroll
    for (int kc = 0; kc < 4; kc++)
      qbf[qg][kc] = *(const bf16x8*)(Qg + kc * 16 + hf * 8);
  }

  const int* mk = mask + b * CT + kv0;
  int localAny = 0;
  for (int i = t; i < 1024; i += 128) localAny |= (mk[i] == 0);
  int anyM = __syncthreads_or(localAny);

  f32x16 oacc[2][2];
  #pragma unroll
  for (int qg = 0; qg < 2; qg++)
    #pragma unroll
    for (int dt = 0; dt < 2; dt++)
      #pragma unroll
      for (int r = 0; r < 16; r++) oacc[qg][dt][r] = 0.f;
  float lp[2] = {0.f, 0.f};

  const u16* Kg0 = Kb + ((size_t)(b * CT + kv0)) * CD + head * CDH;
  const u16* Vg0 = Vb + ((size_t)(b * CT + kv0)) * CD + head * CDH;

  // V prefetch (iter 0): 2 reps x (2 key-rows of 16B)
  int vpr[2], vdg[2];
  uint4 va[2], vb2[2];
  #pragma unroll
  for (int rep = 0; rep < 2; rep++) {
    int u = rep * 128 + t;
    vpr[rep] = u >> 3; vdg[rep] = u & 7;
    const u16* VgT = Vg0 + (size_t)(2 * vpr[rep]) * CD + vdg[rep] * 8;
    va[rep] = *(const uint4*)VgT;
    vb2[rep] = *(const uint4*)(VgT + CD);
  }

  for (int kv = 0; kv < 1024; kv += 64) {
    __syncthreads();
    // stage K (async DMA, swizzled): 512 chunks, 4 per thread
    #pragma unroll
    for (int p = 0; p < 4; p++) {
      int idx = p * 128 + t;
      int row = idx >> 3, cc = (idx & 7) ^ (row & 7);
      gload_lds16(Kg0 + (size_t)(kv + row) * CD + cc * 8,
                  Ks + (size_t)(p * 128 + (t & 64)) * 8);
    }
    // stage V^T from prefetched regs (swizzled writes)
    #pragma unroll
    for (int rep = 0; rep < 2; rep++) {
      const u32* pa = (const u32*)&va[rep];
      const u32* pb = (const u32*)&vb2[rep];
      u32* dst = VsD + (size_t)vdg[rep] * 288 + (vpr[rep] ^ (vdg[rep] << 2));
      #pragma unroll
      for (int j = 0; j < 8; j++) {
        u32 lo_dw = pa[j >> 1], hi_dw = pb[j >> 1];
        u32 pkv = (j & 1) ? __builtin_amdgcn_perm(hi_dw, lo_dw, 0x07060302u)
                          : __builtin_amdgcn_perm(hi_dw, lo_dw, 0x05040100u);
        dst[j * 36] = pkv;
      }
    }
    __syncthreads();
    // prefetch next V tile
    if (kv + 64 < 1024) {
      #pragma unroll
      for (int rep = 0; rep < 2; rep++) {
        const u16* VgT = Vg0 + (size_t)(kv + 64 + 2 * vpr[rep]) * CD + vdg[rep] * 8;
        va[rep] = *(const uint4*)VgT;
        vb2[rep] = *(const uint4*)(VgT + CD);
      }
    }

    #pragma unroll
    for (int kt = 0; kt < 2; kt++) {
      // K A-frags once per kt, shared across both qg
      bf16x8 af[4];
      int key = kt * 32 + c32;
      #pragma unroll
      for (int kc = 0; kc < 4; kc++) {
        int ch = kc * 2 + hf;
        af[kc] = *(const bf16x8*)&Ks[key * 64 + ((ch ^ (key & 7)) * 8)];
      }
      // S^T + softmax + P-frag build per qg
      u32 pfr[2][2][4];
      #pragma unroll
      for (int qg = 0; qg < 2; qg++) {
        f32x16 sv;
        #pragma unroll
        for (int r = 0; r < 16; r++) sv[r] = 0.f;
        #pragma unroll
        for (int kc = 0; kc < 4; kc++)
          sv = __builtin_amdgcn_mfma_f32_32x32x16_bf16(af[kc], qbf[qg][kc], sv, 0, 0, 0);
        u32 pk[8];
        #pragma unroll
        for (int i = 0; i < 8; i++) {
          float x0 = sv[2 * i] * 0.125f, x1 = sv[2 * i + 1] * 0.125f;
          if (anyM) {
            int r0 = 2 * i, r1 = 2 * i + 1;
            int mi0 = kv + kt * 32 + (r0 & 3) + 8 * (r0 >> 2) + 4 * hf;
            int mi1 = kv + kt * 32 + (r1 & 3) + 8 * (r1 >> 2) + 4 * hf;
            x0 += mk[mi0] ? 0.f : -1.0e9f;
            x1 += mk[mi1] ? 0.f : -1.0e9f;
          }
          float p0 = __expf(fminf(x0, 30.f));
          float p1 = __expf(fminf(x1, 30.f));
          lp[qg] += p0 + p1;
          pk[i] = pk2(p0, p1);
        }
        #pragma unroll
        for (int c = 0; c < 2; c++) {
          u32 d0 = pk[4 * c + 0], d2 = pk[4 * c + 2];
          u32 d1 = pk[4 * c + 1], d3 = pk[4 * c + 3];
          plswap(d0, d2, hf);
          plswap(d1, d3, hf);
          pfr[qg][c][0] = d0; pfr[qg][c][1] = d1;
          pfr[qg][c][2] = d2; pfr[qg][c][3] = d3;
        }
      }
      // O^T += V^T * P^T : V-frags loaded once, reused across qg
      #pragma unroll
      for (int c = 0; c < 2; c++) {
        int prb = kt * 16 + c * 8 + hf * 4;
        #pragma unroll
        for (int dt = 0; dt < 2; dt++) {
          int d = dt * 32 + c32;
          const u32* vp = VsD + d * 36 + (prb ^ ((d >> 3) << 2));
          bf16x8 vf = *(const bf16x8*)vp;
          union { u32 u[4]; bf16x8 v; } pf0, pf1;
          #pragma unroll
          for (int q2 = 0; q2 < 4; q2++) { pf0.u[q2] = pfr[0][c][q2]; pf1.u[q2] = pfr[1][c][q2]; }
          oacc[0][dt] = __builtin_amdgcn_mfma_f32_32x32x16_bf16(vf, pf0.v, oacc[0][dt], 0, 0, 0);
          oacc[1][dt] = __builtin_amdgcn_mfma_f32_32x32x16_bf16(vf, pf1.v, oacc[1][dt], 0, 0, 0);
        }
      }
    }
  }

  // epilogue: reduce l across halves, normalize, store partials
  #pragma unroll
  for (int qg = 0; qg < 2; qg++) {
    float lT = lp[qg] + __shfl_xor(lp[qg], 32, 64);
    float linv = 1.f / lT;
    int qrow = w * 64 + qg * 32 + c32;
    u16* Op = Opart + ((size_t)(half * 512 + gid) * 128 + qrow) * 64;
    #pragma unroll
    for (int dt = 0; dt < 2; dt++) {
      #pragma unroll
      for (int g = 0; g < 4; g++) {
        float o0 = oacc[qg][dt][4 * g + 0] * linv, o1 = oacc[qg][dt][4 * g + 1] * linv;
        float o2 = oacc[qg][dt][4 * g + 2] * linv, o3 = oacc[qg][dt][4 * g + 3] * linv;
        uint2 pw;
        pw.x = pk2(o0, o1);
        pw.y = pk2(o2, o3);
        *(uint2*)(Op + dt * 32 + 8 * g + 4 * hf) = pw;
      }
    }
    if (hf == 0)
      Lpart[(size_t)(half * 512 + gid) * 128 + w * 64 + qg * 32 + c32] = lT;
  }
}

// ---------------- combine kv-split partials ----------------
__global__ __launch_bounds__(256) void combine_k(const u16* __restrict__ Opart,
                                                 const float* __restrict__ Lpart,
                                                 u16* __restrict__ Ob) {
  int fid = blockIdx.x * 256 + threadIdx.x;
  int gid = fid >> 11;
  int rem = fid & 2047;
  int r = rem >> 4, d = (rem & 15) * 4;
  int b = gid >> 8, head = (gid >> 4) & 15, qt = gid & 15;
  size_t i0 = ((size_t)gid * 128 + r) * 64 + d;
  size_t i1 = ((size_t)(512 + gid) * 128 + r) * 64 + d;
  uint2 A = *(const uint2*)(Opart + i0);
  uint2 Bv = *(const uint2*)(Opart + i1);
  float la = Lpart[gid * 128 + r], lb = Lpart[(512 + gid) * 128 + r];
  float inv = 1.f / (la + lb);
  float wa = la * inv, wb = lb * inv;
  float o0 = wa * b2f(A.x & 0xffffu) + wb * b2f(Bv.x & 0xffffu);
  float o1 = wa * b2f(A.x >> 16) + wb * b2f(Bv.x >> 16);
  float o2 = wa * b2f(A.y & 0xffffu) + wb * b2f(Bv.y & 0xffffu);
  float o3 = wa * b2f(A.y >> 16) + wb * b2f(Bv.y >> 16);
  uint2 pw;
  pw.x = pk2(o0, o1);
  pw.y = pk2(o2, o3);
  size_t trow = (size_t)b * CT + qt * 128 + r;
  *(uint2*)(Ob + trow * CD + head * CDH + d) = pw;
}

extern "C" void kernel_launch(void* const* d_in, const int* in_sizes, int n_in,
                              void* d_out, int out_size, void* d_ws, size_t ws_size,
                              hipStream_t stream) {
  const float* x  = (const float*)d_in[0];
  const int* mask = (const int*)d_in[1];
  const float* Wq = (const float*)d_in[2];
  const float* Wk = (const float*)d_in[3];
  const float* Wv = (const float*)d_in[4];
  const float* Wo = (const float*)d_in[5];
  float* out = (float*)d_out;

  u16* Xb    = (u16*)d_ws;                         // [4096][1024]
  u16* Wqkv  = Xb + (size_t)4096 * 1024;           // Wq^T|Wk^T|Wv^T|Wo^T [4096][1024]
  u16* WoT   = Wqkv + (size_t)3072 * 1024;
  u16* Qb    = Wqkv + (size_t)4096 * 1024;         // Q,K,V each [4096][1024]
  u16* Ob    = Qb + (size_t)3 * 4096 * 1024;       // attn out [4096][1024]
  u16* Opart = Ob + (size_t)4096 * 1024;           // [2*512][128][64] bf16
  float* Lpart = (float*)(Opart + (size_t)2 * 512 * 128 * 64);  // [2*512][128]

  prep_k<<<8192, 256, 0, stream>>>(x, Wq, Wk, Wv, Wo, Xb, Wqkv);
  gemm_bt_k<u16><<<dim3(24, 32), 256, 0, stream>>>(Xb, Wqkv, Qb, 1024,
                                                   (size_t)4096 * 1024);
  attn_k<<<dim3(16, 16, 4), 128, 0, stream>>>(Qb, Qb + (size_t)4096 * 1024,
                                              Qb + (size_t)2 * 4096 * 1024, mask,
                                              Opart, Lpart);
  combine_k<<<4096, 256, 0, stream>>>(Opart, Lpart, Ob);
  gemm_bt64_k<<<dim3(16, 32), 256, 0, stream>>>(Ob, WoT, out, 1024);
}